// Round 6
// baseline (169.389 us; speedup 1.0000x reference)
//
#include <hip/hip_runtime.h>
#include <math.h>

#define TT 2
#define CC 64
#define HH 160
#define WW 160
#define KS 7
#define K2 49
#define NSPIX 196
#define HWSZ (HH*WW)
#define PAD 3
#define OO 64
#define FANIN (CC*K2)
#define TS 8
#define PS (TS+KS-1)   // 14
#define NPOS (PS*PS)   // 196

#define NCHUNK 50
#define CHUNKPIX 512

typedef short short8 __attribute__((ext_vector_type(8)));
typedef float f32x16 __attribute__((ext_vector_type(16)));

__device__ __forceinline__ int reflect(int i, int n) {
    if (i < 0) i = -i;
    if (i >= n) i = 2*n - 2 - i;
    return i;
}

__device__ __forceinline__ unsigned short f2bf(float f) {
    unsigned int u = __float_as_uint(f);
    unsigned int r = (u + 0x7FFFu + ((u >> 16) & 1u)) >> 16;
    return (unsigned short)r;
}
__device__ __forceinline__ float bf2f(unsigned short s) {
    return __uint_as_float(((unsigned int)s) << 16);
}

// fused prep: blocks [0,800) seg-partials; [800,1000) scale; [1000,1196) Wb build
__global__ __launch_bounds__(256) void k_prep(const float* __restrict__ x,
                                              const int* __restrict__ spix,
                                              const float* __restrict__ Wl,
                                              const float* __restrict__ wsc,
                                              const float* __restrict__ bsc,
                                              float* __restrict__ partials,
                                              float* __restrict__ cntp,
                                              float* __restrict__ scale,
                                              unsigned short* __restrict__ Wb) {
    __shared__ float ls[8*200];
    __shared__ float lcnt[200];
    int bid = blockIdx.x;
    int tid = threadIdx.x;

    if (bid < 800) {
        int cg = bid & 7;
        int rest = bid >> 3;
        int ch = rest % NCHUNK;
        int t  = rest / NCHUNK;

        for (int i = tid; i < 8*200; i += 256) ls[i] = 0.f;
        if (cg == 0) for (int i = tid; i < 200; i += 256) lcnt[i] = 0.f;
        __syncthreads();

        int base = ch*CHUNKPIX;
        const float* xb = x + ((size_t)t*CC + cg*8)*HWSZ;
        #pragma unroll
        for (int i = 0; i < CHUNKPIX; i += 256) {
            int pix = base + i + tid;
            int s = spix[t*HWSZ + pix];
            if (cg == 0) atomicAdd(&lcnt[s], 1.0f);
            #pragma unroll
            for (int j = 0; j < 8; ++j) atomicAdd(&ls[j*200 + s], xb[(size_t)j*HWSZ + pix]);
        }
        __syncthreads();

        float* pb = partials + ((size_t)(t*NCHUNK + ch)*NSPIX)*CC + cg*8;
        for (int i = tid; i < 8*NSPIX; i += 256) {
            int s = i >> 3, j = i & 7;
            pb[s*CC + j] = ls[j*200 + s];
        }
        if (cg == 0)
            for (int i = tid; i < NSPIX; i += 256)
                cntp[(t*NCHUNK + ch)*NSPIX + i] = lcnt[i];
    } else if (bid < 1000) {
        int pix = (bid - 800)*256 + tid;
        if (pix < TT*HWSZ) {
            int t = pix / HWSZ, hw = pix - t*HWSZ;
            const float* xs = x + (size_t)t*CC*HWSZ + hw;
            float s1 = 0.f, s2 = 0.f;
            #pragma unroll 8
            for (int c = 0; c < CC; ++c) { float v = xs[c*HWSZ]; s1 += wsc[c]*v; s2 += v*v; }
            float z = s1/(sqrtf(s2) + 1e-10f) + bsc[0];
            float sp_ = (z > 0.f) ? z + log1pf(expf(-z)) : log1pf(expf(z));
            scale[pix] = 10.f*sp_;
        }
    } else {
        int row = (bid - 1000)*256 + tid;
        if (row < 2*K2*4*64) {
            int ln  = row & 63;
            int kc  = (row >> 6) & 3;
            int tq  = row >> 8;
            int tap = tq % K2;
            int qo  = tq / K2;
            int o = qo*32 + (ln & 31);
            int cb = kc*16 + (ln >> 5)*8;
            unsigned short* dst = Wb + (size_t)row*8;
            const float* src = Wl + (size_t)o*FANIN + tap;
            #pragma unroll
            for (int j = 0; j < 8; ++j) dst[j] = f2bf(src[(size_t)(cb + j)*K2]);
        }
    }
}

// reduce partials -> down, sq (one wave per (t,s); lane = c)
__global__ __launch_bounds__(256) void k_red(const float* __restrict__ partials,
                                             const float* __restrict__ cntp,
                                             float* __restrict__ down,
                                             float* __restrict__ sq) {
    int ts = blockIdx.x*4 + threadIdx.y;
    if (ts >= TT*NSPIX) return;
    int t = ts / NSPIX, s = ts - t*NSPIX;
    int c = threadIdx.x;

    const float* pb = partials + ((size_t)t*NCHUNK*NSPIX + s)*CC + c;
    float acc = 0.f;
    #pragma unroll 10
    for (int ch = 0; ch < NCHUNK; ++ch) acc += pb[(size_t)ch*NSPIX*CC];

    float cv = (c < NCHUNK) ? cntp[(t*NCHUNK + c)*NSPIX + s] : 0.f;
    #pragma unroll
    for (int off = 1; off < 64; off <<= 1) cv += __shfl_xor(cv, off, 64);

    float d = acc / fmaxf(cv, 1.0f);
    down[ts*CC + c] = d;
    float v = d*d;
    #pragma unroll
    for (int off = 1; off < 64; off <<= 1) v += __shfl_xor(v, off, 64);
    if (c == 0) sq[ts] = v;
}

__global__ void k_pwd(const float* __restrict__ down, const float* __restrict__ sq,
                      float* __restrict__ pwd) {
    int tid = blockIdx.x*256 + threadIdx.x;
    if (tid >= TT*NSPIX*NSPIX) return;
    int t = tid / (NSPIX*NSPIX); int r = tid - t*NSPIX*NSPIX;
    int s = r / NSPIX, u = r - (r / NSPIX)*NSPIX;
    const float* ds = down + (t*NSPIX + s)*CC;
    const float* du = down + (t*NSPIX + u)*CC;
    float dot = 0.f;
    #pragma unroll 4
    for (int c = 0; c < CC; ++c) dot += ds[c]*du[c];
    float v = sq[t*NSPIX + s] + sq[t*NSPIX + u] - 2.f*dot;
    pwd[tid] = fmaxf(v, 0.f);
}

// per-tile normalized rw in bf16: rw_g[tile][tap][64 pixels]
__global__ __launch_bounds__(256) void k_rw(const int* __restrict__ spix,
                                            const float* __restrict__ pwd,
                                            const float* __restrict__ scale,
                                            unsigned short* __restrict__ rw_g) {
    __shared__ int   sp[NPOS];
    __shared__ float rwt[K2*64];
    __shared__ float mxp[4*64];
    __shared__ float mxl[64];

    int bid = blockIdx.x;
    int t = bid / 400;
    int r = bid - t*400;
    int th0 = (r / 20)*TS, tw0 = (r - (r/20)*20)*TS;
    int tid = threadIdx.y*64 + threadIdx.x;

    for (int i = tid; i < NPOS; i += 256) {
        int rr = reflect(th0 + i/PS - PAD, HH);
        int cc = reflect(tw0 + i%PS - PAD, WW);
        sp[i] = spix[t*HWSZ + rr*WW + cc];
    }
    __syncthreads();

    int p_ = threadIdx.x;
    int ty = threadIdx.y;
    int py0 = p_ >> 3, px0 = p_ & 7;
    {
        float sc = scale[t*HWSZ + (th0 + py0)*WW + (tw0 + px0)];
        int s0 = sp[(py0 + PAD)*PS + (px0 + PAD)];
        const float* pr = pwd + (t*NSPIX + s0)*NSPIX;
        float pmax = 0.f;
        for (int k = ty; k < K2; k += 4) {
            int di = k/KS, dj = k - di*KS;
            int nb = sp[(py0 + di)*PS + (px0 + dj)];
            float v = expf(-sc * pr[nb]);
            rwt[k*64 + p_] = v;
            pmax = fmaxf(pmax, v);
        }
        mxp[ty*64 + p_] = pmax;
    }
    __syncthreads();
    if (ty == 0) {
        float m = fmaxf(fmaxf(mxp[p_], mxp[64 + p_]), fmaxf(mxp[128 + p_], mxp[192 + p_]));
        mxl[p_] = 1.f/(1e-5f + m);
    }
    __syncthreads();
    // normalize + pack to bf16 pairs, coalesced uint stores
    unsigned int* dst = (unsigned int*)(rw_g + (size_t)bid*K2*64);
    for (int i = tid; i < K2*32; i += 256) {
        int k = i >> 5;             // tap
        int pp = (i & 31)*2;        // pixel pair
        float v0 = rwt[k*64 + pp]     * mxl[pp];
        float v1 = rwt[k*64 + pp + 1] * mxl[pp + 1];
        dst[i] = (unsigned int)f2bf(v0) | ((unsigned int)f2bf(v1) << 16);
    }
}

// MFMA main (slim): stage xpT + rwb, 1 barrier, tap loop, K-reduce, store.
// Block = 8x8 pixel tile, 4 waves = (kh: K-half) x (qp: pix-half).
__global__ __launch_bounds__(256, 4) void k_main(
    const float* __restrict__ x,
    const unsigned short* __restrict__ Wb, const float* __restrict__ b_lin,
    const unsigned short* __restrict__ rw_g,
    float* __restrict__ out)
{
    __shared__ unsigned short xpT[NPOS*64];   // 25088 B, swizzled
    __shared__ unsigned short rwb[K2*64];     // 6272 B

    int bid = blockIdx.x;
    int t = bid / 400;
    int r = bid - t*400;
    int th0 = (r / 20)*TS, tw0 = (r - (r/20)*20)*TS;
    int tid = threadIdx.y*64 + threadIdx.x;

    // stage x -> bf16 xpT[pos][c] with 16B-chunk XOR swizzle
    for (int i = tid; i < NPOS*32; i += 256) {
        int pos = i % NPOS;
        int cp  = i / NPOS;
        int rr = reflect(th0 + pos/PS - PAD, HH);
        int cc = reflect(tw0 + pos%PS - PAD, WW);
        const float* xs = x + ((size_t)t*CC + 2*cp)*HWSZ + rr*WW + cc;
        float v0 = xs[0];
        float v1 = xs[HWSZ];
        unsigned int pk = (unsigned int)f2bf(v0) | ((unsigned int)f2bf(v1) << 16);
        int idx = pos*64 + (((cp >> 2) ^ (pos & 7)) << 3) + (cp & 3)*2;
        *(unsigned int*)&xpT[idx] = pk;
    }
    // stage rwb (coalesced)
    {
        const unsigned int* src = (const unsigned int*)(rw_g + (size_t)bid*K2*64);
        unsigned int* d = (unsigned int*)rwb;
        for (int i = tid; i < K2*32; i += 256) d[i] = src[i];
    }
    __syncthreads();

    int ln = threadIdx.x;
    int wv = __builtin_amdgcn_readfirstlane(threadIdx.y);
    int qp = wv & 1, kh = wv >> 1;
    int p  = qp*32 + (ln & 31);
    int ppy = p >> 3, ppx = p & 7;
    int kc0 = 2*kh, kc1 = 2*kh + 1;
    int lhi = ln >> 5;

    const unsigned short* A00b = Wb + (size_t)kc0*512 + ln*8;   // qo=0
    const unsigned short* A10b = A00b + (size_t)K2*4*512;       // qo=1

    f32x16 Czero;
    #pragma unroll
    for (int i = 0; i < 16; ++i) Czero[i] = 0.f;
    f32x16 acc0 = Czero, acc1 = Czero;

    int jc0 = 2*kc0 + lhi, jc1 = 2*kc1 + lhi;

    int di = 0, dj = 0;
    #pragma unroll 7
    for (int tap = 0; tap < K2; ++tap) {
        const unsigned short* a0 = A00b + tap*2048;
        short8 A00 = *(const short8*)(a0);
        short8 A01 = *(const short8*)(a0 + 512);
        const unsigned short* a1 = A10b + tap*2048;
        short8 A10 = *(const short8*)(a1);
        short8 A11 = *(const short8*)(a1 + 512);

        int pos = (ppy + di)*PS + (ppx + dj);
        int sw  = pos & 7;
        const unsigned short* bbase = &xpT[pos*64];
        short8 B0 = *(const short8*)(bbase + ((jc0 ^ sw) << 3));
        short8 B1 = *(const short8*)(bbase + ((jc1 ^ sw) << 3));

        f32x16 C0 = __builtin_amdgcn_mfma_f32_32x32x16_bf16(A00, B0, Czero, 0, 0, 0);
        C0 = __builtin_amdgcn_mfma_f32_32x32x16_bf16(A01, B1, C0, 0, 0, 0);
        f32x16 C1 = __builtin_amdgcn_mfma_f32_32x32x16_bf16(A10, B0, Czero, 0, 0, 0);
        C1 = __builtin_amdgcn_mfma_f32_32x32x16_bf16(A11, B1, C1, 0, 0, 0);

        float rwv = bf2f(rwb[tap*64 + p]);
        #pragma unroll
        for (int i = 0; i < 16; ++i) acc0[i] = fmaf(C0[i], rwv, acc0[i]);
        #pragma unroll
        for (int i = 0; i < 16; ++i) acc1[i] = fmaf(C1[i], rwv, acc1[i]);

        if (++dj == KS) { dj = 0; ++di; }
    }

    // cross-wave K-reduction (reuse xpT as f32 buffer)
    __syncthreads();
    float* red = (float*)xpT;
    if (kh == 1) {
        #pragma unroll
        for (int i = 0; i < 16; ++i) {
            red[i*128 + qp*64 + ln]        = acc0[i];
            red[(16 + i)*128 + qp*64 + ln] = acc1[i];
        }
    }
    __syncthreads();
    if (kh == 0) {
        int h = th0 + ppy, w = tw0 + ppx;
        int row_hi = 4*lhi;
        float* ob = out + (size_t)t*OO*HWSZ + h*WW + w;
        #pragma unroll
        for (int rg = 0; rg < 16; ++rg) {
            float v0 = acc0[rg] + red[rg*128 + qp*64 + ln];
            float v1 = acc1[rg] + red[(16 + rg)*128 + qp*64 + ln];
            int o0 = (rg & 3) + 8*(rg >> 2) + row_hi;
            int o1 = 32 + o0;
            ob[(size_t)o0*HWSZ] = v0 + b_lin[o0];
            ob[(size_t)o1*HWSZ] = v1 + b_lin[o1];
        }
    }
}

extern "C" void kernel_launch(void* const* d_in, const int* in_sizes, int n_in,
                              void* d_out, int out_size, void* d_ws, size_t ws_size,
                              hipStream_t stream) {
    const float* x    = (const float*)d_in[0];
    const int*   spix = (const int*)d_in[1];
    const float* Wl   = (const float*)d_in[2];
    const float* bl   = (const float*)d_in[3];
    const float* wsc  = (const float*)d_in[4];
    const float* bsc  = (const float*)d_in[5];
    float* out = (float*)d_out;

    float* ws    = (float*)d_ws;
    float* down  = ws;                           // 25088
    float* sq    = down + TT*NSPIX*CC;           // 392
    float* pwd   = sq   + TT*NSPIX;              // 76832
    float* scale = pwd  + TT*NSPIX*NSPIX;        // 51200
    float* cntp  = scale + TT*HWSZ;              // 19600
    float* parts = cntp + TT*NCHUNK*NSPIX;       // 1254400 f32 (5.02 MB)
    unsigned short* Wb = (unsigned short*)(parts + (size_t)TT*NCHUNK*NSPIX*CC);
    // rw_g overlays parts: parts fully consumed by k_red before k_rw writes (stream-ordered)
    unsigned short* rw_g = (unsigned short*)parts;   // 800*49*64 ushorts = 5.02 MB

    k_prep<<<1196, 256, 0, stream>>>(x, spix, Wl, wsc, bsc, parts, cntp, scale, Wb);
    {
        dim3 blk(64, 4, 1);
        k_red <<<(TT*NSPIX + 3)/4, blk, 0, stream>>>(parts, cntp, down, sq);
    }
    k_pwd <<<(TT*NSPIX*NSPIX + 255)/256, 256, 0, stream>>>(down, sq, pwd);
    {
        dim3 blk(64, 4, 1);
        k_rw  <<<TT*400, blk, 0, stream>>>(spix, pwd, scale, rw_g);
    }

    dim3 blk(64, 4, 1);
    k_main<<<TT*400, blk, 0, stream>>>(x, Wb, bl, rw_g, out);
}

// Round 7
// 159.137 us; speedup vs baseline: 1.0644x; 1.0644x over previous
//
#include <hip/hip_runtime.h>
#include <math.h>

#define TT 2
#define CC 64
#define HH 160
#define WW 160
#define KS 7
#define K2 49
#define NSPIX 196
#define HWSZ (HH*WW)
#define PAD 3
#define OO 64
#define FANIN (CC*K2)
#define TS 8
#define PS (TS+KS-1)   // 14
#define NPOS (PS*PS)   // 196

#define NCHUNK 50
#define CHUNKPIX 512

typedef short short8 __attribute__((ext_vector_type(8)));
typedef float f32x16 __attribute__((ext_vector_type(16)));

__device__ __forceinline__ int reflect(int i, int n) {
    if (i < 0) i = -i;
    if (i >= n) i = 2*n - 2 - i;
    return i;
}

__device__ __forceinline__ unsigned short f2bf(float f) {
    unsigned int u = __float_as_uint(f);
    unsigned int r = (u + 0x7FFFu + ((u >> 16) & 1u)) >> 16;
    return (unsigned short)r;
}
__device__ __forceinline__ float bf2f(unsigned short s) {
    return __uint_as_float(((unsigned int)s) << 16);
}

// fused prep: [0,800) seg (LDS accumulate + atomic flush to sums/cnts);
//             [800,1000) scale; [1000,1196) Wb build
__global__ __launch_bounds__(256) void k_prep(const float* __restrict__ x,
                                              const int* __restrict__ spix,
                                              const float* __restrict__ Wl,
                                              const float* __restrict__ wsc,
                                              const float* __restrict__ bsc,
                                              float* __restrict__ sums,
                                              float* __restrict__ cnts,
                                              float* __restrict__ scale,
                                              unsigned short* __restrict__ Wb) {
    __shared__ float ls[8*200];
    __shared__ float lcnt[200];
    int bid = blockIdx.x;
    int tid = threadIdx.x;

    if (bid < 800) {
        int cg = bid & 7;
        int rest = bid >> 3;
        int ch = rest % NCHUNK;
        int t  = rest / NCHUNK;

        for (int i = tid; i < 8*200; i += 256) ls[i] = 0.f;
        if (cg == 0) for (int i = tid; i < 200; i += 256) lcnt[i] = 0.f;
        __syncthreads();

        int base = ch*CHUNKPIX;
        const float* xb = x + ((size_t)t*CC + cg*8)*HWSZ;
        #pragma unroll
        for (int i = 0; i < CHUNKPIX; i += 256) {
            int pix = base + i + tid;
            int s = spix[t*HWSZ + pix];
            if (cg == 0) atomicAdd(&lcnt[s], 1.0f);
            #pragma unroll
            for (int j = 0; j < 8; ++j) atomicAdd(&ls[j*200 + s], xb[(size_t)j*HWSZ + pix]);
        }
        __syncthreads();

        // atomic flush (sums zeroed by host-side memsetAsync)
        float* sb = sums + (size_t)t*NSPIX*CC + cg*8;
        for (int i = tid; i < 8*NSPIX; i += 256) {
            int s = i >> 3, j = i & 7;
            float v = ls[j*200 + s];
            if (v != 0.f) atomicAdd(&sb[s*CC + j], v);
        }
        if (cg == 0)
            for (int i = tid; i < NSPIX; i += 256) {
                float v = lcnt[i];
                if (v != 0.f) atomicAdd(&cnts[t*NSPIX + i], v);
            }
    } else if (bid < 1000) {
        int pix = (bid - 800)*256 + tid;
        if (pix < TT*HWSZ) {
            int t = pix / HWSZ, hw = pix - t*HWSZ;
            const float* xs = x + (size_t)t*CC*HWSZ + hw;
            float s1 = 0.f, s2 = 0.f;
            #pragma unroll 8
            for (int c = 0; c < CC; ++c) { float v = xs[c*HWSZ]; s1 += wsc[c]*v; s2 += v*v; }
            float z = s1/(sqrtf(s2) + 1e-10f) + bsc[0];
            float sp_ = (z > 0.f) ? z + log1pf(expf(-z)) : log1pf(expf(z));
            scale[pix] = 10.f*sp_;
        }
    } else {
        int row = (bid - 1000)*256 + tid;
        if (row < 2*K2*4*64) {
            int ln  = row & 63;
            int kc  = (row >> 6) & 3;
            int tq  = row >> 8;
            int tap = tq % K2;
            int qo  = tq / K2;
            int o = qo*32 + (ln & 31);
            int cb = kc*16 + (ln >> 5)*8;
            unsigned short* dst = Wb + (size_t)row*8;
            const float* src = Wl + (size_t)o*FANIN + tap;
            #pragma unroll
            for (int j = 0; j < 8; ++j) dst[j] = f2bf(src[(size_t)(cb + j)*K2]);
        }
    }
}

// pwd directly from sums/cnts: pwd[t,s,u] = sum_c (down_s[c]-down_u[c])^2
__global__ __launch_bounds__(256) void k_pwd(const float* __restrict__ sums,
                                             const float* __restrict__ cnts,
                                             float* __restrict__ pwd) {
    int tid = blockIdx.x*256 + threadIdx.x;
    if (tid >= TT*NSPIX*NSPIX) return;
    int t = tid / (NSPIX*NSPIX); int r = tid - t*NSPIX*NSPIX;
    int s = r / NSPIX, u = r - (r / NSPIX)*NSPIX;
    const float* ds = sums + (size_t)(t*NSPIX + s)*CC;
    const float* du = sums + (size_t)(t*NSPIX + u)*CC;
    float is = 1.0f / fmaxf(cnts[t*NSPIX + s], 1.0f);
    float iu = 1.0f / fmaxf(cnts[t*NSPIX + u], 1.0f);
    float acc = 0.f;
    #pragma unroll 8
    for (int c = 0; c < CC; ++c) {
        float d = ds[c]*is - du[c]*iu;
        acc = fmaf(d, d, acc);
    }
    pwd[tid] = acc;
}

// MFMA main. Block = 8x8 pixel tile, 4 waves = (qo = wv&1, kh = wv>>1).
// Each wave: its kc-pair (K-half), its o-half, BOTH 32-pixel groups ->
// every W-fragment read exactly once per block (A L2 traffic halved).
// rw computed in-kernel. Cross-kh reduction via LDS at the end.
__global__ __launch_bounds__(256, 4) void k_main(
    const float* __restrict__ x, const int* __restrict__ spix,
    const unsigned short* __restrict__ Wb, const float* __restrict__ b_lin,
    const float* __restrict__ pwd, const float* __restrict__ scale,
    float* __restrict__ out)
{
    __shared__ unsigned short xpT[NPOS*64];   // 25088 B, XOR-swizzled
    __shared__ unsigned short rwb[K2*64];     // 6272 B
    __shared__ int   sp[NPOS];                // 784 B
    __shared__ float mxp[4*64];               // 1024 B
    __shared__ float mxl[64];                 // 256 B

    int bid = blockIdx.x;
    int t = bid / 400;
    int r = bid - t*400;
    int th0 = (r / 20)*TS, tw0 = (r - (r/20)*20)*TS;
    int tid = threadIdx.y*64 + threadIdx.x;

    for (int i = tid; i < NPOS; i += 256) {
        int rr = reflect(th0 + i/PS - PAD, HH);
        int cc = reflect(tw0 + i%PS - PAD, WW);
        sp[i] = spix[t*HWSZ + rr*WW + cc];
    }
    // stage x -> bf16 xpT[pos][c] with 16B-chunk XOR swizzle
    for (int i = tid; i < NPOS*32; i += 256) {
        int pos = i % NPOS;
        int cp  = i / NPOS;
        int rr = reflect(th0 + pos/PS - PAD, HH);
        int cc = reflect(tw0 + pos%PS - PAD, WW);
        const float* xs = x + ((size_t)t*CC + 2*cp)*HWSZ + rr*WW + cc;
        float v0 = xs[0];
        float v1 = xs[HWSZ];
        unsigned int pk = (unsigned int)f2bf(v0) | ((unsigned int)f2bf(v1) << 16);
        int idx = pos*64 + (((cp >> 2) ^ (pos & 7)) << 3) + (cp & 3)*2;
        *(unsigned int*)&xpT[idx] = pk;
    }
    __syncthreads();

    // rw build (bf16, normalized per pixel)
    int p_ = threadIdx.x;
    int ty = threadIdx.y;
    int py0 = p_ >> 3, px0 = p_ & 7;
    {
        float sc = scale[t*HWSZ + (th0 + py0)*WW + (tw0 + px0)];
        int s0 = sp[(py0 + PAD)*PS + (px0 + PAD)];
        const float* pr = pwd + (t*NSPIX + s0)*NSPIX;
        float pmax = 0.f;
        for (int k = ty; k < K2; k += 4) {
            int di = k/KS, dj = k - di*KS;
            int nb = sp[(py0 + di)*PS + (px0 + dj)];
            float v = expf(-sc * pr[nb]);
            rwb[k*64 + p_] = f2bf(v);
            pmax = fmaxf(pmax, v);
        }
        mxp[ty*64 + p_] = pmax;
    }
    __syncthreads();
    if (ty == 0) {
        float m = fmaxf(fmaxf(mxp[p_], mxp[64 + p_]), fmaxf(mxp[128 + p_], mxp[192 + p_]));
        mxl[p_] = 1.f/(1e-5f + m);
    }
    __syncthreads();
    {
        float s = mxl[p_];
        for (int k = ty; k < K2; k += 4)
            rwb[k*64 + p_] = f2bf(bf2f(rwb[k*64 + p_]) * s);
    }
    __syncthreads();

    int ln = threadIdx.x;
    int wv = __builtin_amdgcn_readfirstlane(threadIdx.y);
    int qo = wv & 1, kh = wv >> 1;
    int lhi = ln >> 5;
    int l31 = ln & 31;
    int p0 = l31, p1 = 32 + l31;          // both pixel groups
    int ppy0 = p0 >> 3, ppx0 = p0 & 7;    // pg1: ppy0+4, same ppx

    int kc0 = 2*kh;
    int jc0 = 4*kh + lhi, jc1 = 4*kh + 2 + lhi;

    const unsigned short* Ab = Wb + ((size_t)(qo*K2*4) + kc0)*512 + ln*8;

    f32x16 Czero;
    #pragma unroll
    for (int i = 0; i < 16; ++i) Czero[i] = 0.f;
    f32x16 acc0 = Czero, acc1 = Czero;

    int di = 0, dj = 0;
    #pragma unroll 7
    for (int tap = 0; tap < K2; ++tap) {
        const unsigned short* a = Ab + (size_t)tap*2048;
        short8 A0 = *(const short8*)(a);
        short8 A1 = *(const short8*)(a + 512);

        int pos0 = (ppy0 + di)*PS + (ppx0 + dj);
        int sw   = pos0 & 7;                    // pos1 = pos0+56, 56&7==0 -> same sw
        const unsigned short* b0 = &xpT[pos0*64];
        const unsigned short* b1 = b0 + 56*64;
        short8 B00 = *(const short8*)(b0 + ((jc0 ^ sw) << 3));
        short8 B01 = *(const short8*)(b0 + ((jc1 ^ sw) << 3));
        short8 B10 = *(const short8*)(b1 + ((jc0 ^ sw) << 3));
        short8 B11 = *(const short8*)(b1 + ((jc1 ^ sw) << 3));

        f32x16 C0 = __builtin_amdgcn_mfma_f32_32x32x16_bf16(A0, B00, Czero, 0, 0, 0);
        C0 = __builtin_amdgcn_mfma_f32_32x32x16_bf16(A1, B01, C0, 0, 0, 0);
        f32x16 C1 = __builtin_amdgcn_mfma_f32_32x32x16_bf16(A0, B10, Czero, 0, 0, 0);
        C1 = __builtin_amdgcn_mfma_f32_32x32x16_bf16(A1, B11, C1, 0, 0, 0);

        float rwv0 = bf2f(rwb[tap*64 + p0]);
        float rwv1 = bf2f(rwb[tap*64 + p1]);
        #pragma unroll
        for (int i = 0; i < 16; ++i) acc0[i] = fmaf(C0[i], rwv0, acc0[i]);
        #pragma unroll
        for (int i = 0; i < 16; ++i) acc1[i] = fmaf(C1[i], rwv1, acc1[i]);

        if (++dj == KS) { dj = 0; ++di; }
    }

    // cross-kh reduction (reuse xpT as f32 buffer: (qo,pg,reg) x 64 lanes = 16 KB)
    __syncthreads();
    float* red = (float*)xpT;
    if (kh == 1) {
        #pragma unroll
        for (int i = 0; i < 16; ++i) {
            red[((qo*2 + 0)*16 + i)*64 + ln] = acc0[i];
            red[((qo*2 + 1)*16 + i)*64 + ln] = acc1[i];
        }
    }
    __syncthreads();
    if (kh == 0) {
        int h0 = th0 + ppy0, w0 = tw0 + ppx0;
        int row_hi = 4*lhi;
        float* ob0 = out + (size_t)t*OO*HWSZ + h0*WW + w0;
        float* ob1 = ob0 + 4*WW;   // pg1: h0+4, same w
        #pragma unroll
        for (int rg = 0; rg < 16; ++rg) {
            int o = qo*32 + (rg & 3) + 8*(rg >> 2) + row_hi;
            float v0 = acc0[rg] + red[((qo*2 + 0)*16 + rg)*64 + ln];
            float v1 = acc1[rg] + red[((qo*2 + 1)*16 + rg)*64 + ln];
            float bl = b_lin[o];
            ob0[(size_t)o*HWSZ] = v0 + bl;
            ob1[(size_t)o*HWSZ] = v1 + bl;
        }
    }
}

extern "C" void kernel_launch(void* const* d_in, const int* in_sizes, int n_in,
                              void* d_out, int out_size, void* d_ws, size_t ws_size,
                              hipStream_t stream) {
    const float* x    = (const float*)d_in[0];
    const int*   spix = (const int*)d_in[1];
    const float* Wl   = (const float*)d_in[2];
    const float* bl   = (const float*)d_in[3];
    const float* wsc  = (const float*)d_in[4];
    const float* bsc  = (const float*)d_in[5];
    float* out = (float*)d_out;

    float* ws    = (float*)d_ws;
    float* sums  = ws;                           // 25088
    float* cnts  = sums + TT*NSPIX*CC;           // 392
    float* pwd   = cnts + TT*NSPIX;              // 76832
    float* scale = pwd  + TT*NSPIX*NSPIX;        // 51200
    unsigned short* Wb = (unsigned short*)(scale + TT*HWSZ);  // 200704 ushorts

    hipMemsetAsync(sums, 0, (size_t)(TT*NSPIX*CC + TT*NSPIX)*sizeof(float), stream);

    k_prep<<<1196, 256, 0, stream>>>(x, spix, Wl, wsc, bsc, sums, cnts, scale, Wb);
    k_pwd <<<(TT*NSPIX*NSPIX + 255)/256, 256, 0, stream>>>(sums, cnts, pwd);

    dim3 blk(64, 4, 1);
    k_main<<<TT*400, blk, 0, stream>>>(x, spix, Wb, bl, pwd, scale, out);
}

// Round 8
// 153.017 us; speedup vs baseline: 1.1070x; 1.0400x over previous
//
#include <hip/hip_runtime.h>
#include <math.h>

#define TT 2
#define CC 64
#define HH 160
#define WW 160
#define KS 7
#define K2 49
#define NSPIX 196
#define HWSZ (HH*WW)
#define PAD 3
#define OO 64
#define FANIN (CC*K2)
#define TS 8
#define PS (TS+KS-1)   // 14
#define NPOS (PS*PS)   // 196

#define NCHUNK 50
#define CHUNKPIX 512

typedef _Float16 half8 __attribute__((ext_vector_type(8)));
typedef float f32x16 __attribute__((ext_vector_type(16)));
typedef unsigned int uint4v __attribute__((ext_vector_type(4)));
typedef _Float16 half2v __attribute__((ext_vector_type(2)));

__device__ __forceinline__ int reflect(int i, int n) {
    if (i < 0) i = -i;
    if (i >= n) i = 2*n - 2 - i;
    return i;
}

// fused prep: [0,800) seg (LDS accumulate + atomic flush to sums/cnts);
//             [800,1000) scale + xT (f16 transposed) emit; [1000,1196) Wb (f16) build
__global__ __launch_bounds__(256) void k_prep(const float* __restrict__ x,
                                              const int* __restrict__ spix,
                                              const float* __restrict__ Wl,
                                              const float* __restrict__ wsc,
                                              const float* __restrict__ bsc,
                                              float* __restrict__ sums,
                                              float* __restrict__ cnts,
                                              float* __restrict__ scale,
                                              _Float16* __restrict__ Wb,
                                              _Float16* __restrict__ xT) {
    __shared__ float ls[8*200];
    __shared__ float lcnt[200];
    int bid = blockIdx.x;
    int tid = threadIdx.x;

    if (bid < 800) {
        int cg = bid & 7;
        int rest = bid >> 3;
        int ch = rest % NCHUNK;
        int t  = rest / NCHUNK;

        for (int i = tid; i < 8*200; i += 256) ls[i] = 0.f;
        if (cg == 0) for (int i = tid; i < 200; i += 256) lcnt[i] = 0.f;
        __syncthreads();

        int base = ch*CHUNKPIX;
        const float* xb = x + ((size_t)t*CC + cg*8)*HWSZ;
        #pragma unroll
        for (int i = 0; i < CHUNKPIX; i += 256) {
            int pix = base + i + tid;
            int s = spix[t*HWSZ + pix];
            if (cg == 0) atomicAdd(&lcnt[s], 1.0f);
            #pragma unroll
            for (int j = 0; j < 8; ++j) atomicAdd(&ls[j*200 + s], xb[(size_t)j*HWSZ + pix]);
        }
        __syncthreads();

        float* sb = sums + (size_t)t*NSPIX*CC + cg*8;
        for (int i = tid; i < 8*NSPIX; i += 256) {
            int s = i >> 3, j = i & 7;
            float v = ls[j*200 + s];
            if (v != 0.f) atomicAdd(&sb[s*CC + j], v);
        }
        if (cg == 0)
            for (int i = tid; i < NSPIX; i += 256) {
                float v = lcnt[i];
                if (v != 0.f) atomicAdd(&cnts[t*NSPIX + i], v);
            }
    } else if (bid < 1000) {
        int pix = (bid - 800)*256 + tid;
        int t = pix / HWSZ, hw = pix - t*HWSZ;
        const float* xs = x + (size_t)t*CC*HWSZ + hw;
        float s1 = 0.f, s2 = 0.f;
        unsigned int pk[32];
        #pragma unroll
        for (int cp = 0; cp < 32; ++cp) {
            float v0 = xs[(size_t)(2*cp)*HWSZ];
            float v1 = xs[(size_t)(2*cp + 1)*HWSZ];
            s1 += wsc[2*cp]*v0 + wsc[2*cp+1]*v1;
            s2 = fmaf(v0, v0, s2); s2 = fmaf(v1, v1, s2);
            half2v h; h[0] = (_Float16)v0; h[1] = (_Float16)v1;
            pk[cp] = __builtin_bit_cast(unsigned int, h);
        }
        float z = s1/(sqrtf(s2) + 1e-10f) + bsc[0];
        float sp_ = (z > 0.f) ? z + log1pf(expf(-z)) : log1pf(expf(z));
        scale[pix] = 10.f*sp_;
        uint4v* dst = (uint4v*)(xT + (size_t)pix*64);
        #pragma unroll
        for (int q = 0; q < 8; ++q) {
            uint4v v = { pk[4*q], pk[4*q+1], pk[4*q+2], pk[4*q+3] };
            dst[q] = v;
        }
    } else {
        int row = (bid - 1000)*256 + tid;
        if (row < 2*K2*4*64) {
            int ln  = row & 63;
            int kc  = (row >> 6) & 3;
            int tq  = row >> 8;
            int tap = tq % K2;
            int qo  = tq / K2;
            int o = qo*32 + (ln & 31);
            int cb = kc*16 + (ln >> 5)*8;
            _Float16* dst = Wb + (size_t)row*8;
            const float* src = Wl + (size_t)o*FANIN + tap;
            #pragma unroll
            for (int j = 0; j < 8; ++j) dst[j] = (_Float16)src[(size_t)(cb + j)*K2];
        }
    }
}

// pwd directly from sums/cnts: pwd[t,s,u] = sum_c (down_s[c]-down_u[c])^2
__global__ __launch_bounds__(256) void k_pwd(const float* __restrict__ sums,
                                             const float* __restrict__ cnts,
                                             float* __restrict__ pwd) {
    int tid = blockIdx.x*256 + threadIdx.x;
    if (tid >= TT*NSPIX*NSPIX) return;
    int t = tid / (NSPIX*NSPIX); int r = tid - t*NSPIX*NSPIX;
    int s = r / NSPIX, u = r - (r / NSPIX)*NSPIX;
    const float* ds = sums + (size_t)(t*NSPIX + s)*CC;
    const float* du = sums + (size_t)(t*NSPIX + u)*CC;
    float is = 1.0f / fmaxf(cnts[t*NSPIX + s], 1.0f);
    float iu = 1.0f / fmaxf(cnts[t*NSPIX + u], 1.0f);
    float acc = 0.f;
    #pragma unroll 8
    for (int c = 0; c < CC; ++c) {
        float d = ds[c]*is - du[c]*iu;
        acc = fmaf(d, d, acc);
    }
    pwd[tid] = acc;
}

// MFMA main. Block = 8x8 pixel tile, 4 waves = (qp = wv&1, kh = wv>>1).
// rw folded into B via v_pk_mul_f16 -> single accumulating MFMA chain, no
// per-tap C-restart / rescale. xpT staged from pre-transposed f16 xT.
__global__ __launch_bounds__(256, 4) void k_main(
    const _Float16* __restrict__ xT, const int* __restrict__ spix,
    const _Float16* __restrict__ Wb, const float* __restrict__ b_lin,
    const float* __restrict__ pwd, const float* __restrict__ scale,
    float* __restrict__ out)
{
    __shared__ unsigned short xpT[NPOS*64];   // 25088 B, XOR-swizzled f16
    __shared__ unsigned short rwb[K2*64];     // 6272 B (f16)
    __shared__ int   sp[NPOS];                // 784 B
    __shared__ float mxp[4*64];               // 1024 B
    __shared__ float mxl[64];                 // 256 B

    int bid = blockIdx.x;
    int t = bid / 400;
    int r = bid - t*400;
    int th0 = (r / 20)*TS, tw0 = (r - (r/20)*20)*TS;
    int tid = threadIdx.y*64 + threadIdx.x;

    for (int i = tid; i < NPOS; i += 256) {
        int rr = reflect(th0 + i/PS - PAD, HH);
        int cc = reflect(tw0 + i%PS - PAD, WW);
        sp[i] = spix[t*HWSZ + rr*WW + cc];
    }
    // stage xpT from xT: coalesced 16B loads, XOR-swizzled 16B-chunk writes
    {
        const _Float16* xt = xT + (size_t)t*HWSZ*64;
        for (int i = tid; i < NPOS*8; i += 256) {
            int pos = i >> 3, cb = i & 7;
            int rr = reflect(th0 + pos/PS - PAD, HH);
            int cc = reflect(tw0 + pos%PS - PAD, WW);
            uint4v v = *(const uint4v*)(xt + (size_t)(rr*WW + cc)*64 + cb*8);
            int chunk = cb ^ (pos & 7);
            *(uint4v*)&xpT[pos*64 + chunk*8] = v;
        }
    }
    __syncthreads();

    // rw build (f16, normalized per pixel)
    int p_ = threadIdx.x;
    int ty = threadIdx.y;
    int py0 = p_ >> 3, px0 = p_ & 7;
    {
        float sc = scale[t*HWSZ + (th0 + py0)*WW + (tw0 + px0)];
        int s0 = sp[(py0 + PAD)*PS + (px0 + PAD)];
        const float* pr = pwd + (t*NSPIX + s0)*NSPIX;
        float pmax = 0.f;
        for (int k = ty; k < K2; k += 4) {
            int di = k/KS, dj = k - di*KS;
            int nb = sp[(py0 + di)*PS + (px0 + dj)];
            float v = expf(-sc * pr[nb]);
            rwb[k*64 + p_] = __builtin_bit_cast(unsigned short, (_Float16)v);
            pmax = fmaxf(pmax, v);
        }
        mxp[ty*64 + p_] = pmax;
    }
    __syncthreads();
    if (ty == 0) {
        float m = fmaxf(fmaxf(mxp[p_], mxp[64 + p_]), fmaxf(mxp[128 + p_], mxp[192 + p_]));
        mxl[p_] = 1.f/(1e-5f + m);
    }
    __syncthreads();
    {
        float s = mxl[p_];
        for (int k = ty; k < K2; k += 4) {
            float v = (float)__builtin_bit_cast(_Float16, rwb[k*64 + p_]) * s;
            rwb[k*64 + p_] = __builtin_bit_cast(unsigned short, (_Float16)v);
        }
    }
    __syncthreads();

    int ln = threadIdx.x;
    int wv = __builtin_amdgcn_readfirstlane(threadIdx.y);
    int qp = wv & 1, kh = wv >> 1;
    int p  = qp*32 + (ln & 31);
    int ppy = p >> 3, ppx = p & 7;
    int lhi = ln >> 5;

    int jc0 = 4*kh + lhi, jc1 = jc0 + 2;

    const _Float16* A0b = Wb + (size_t)(2*kh)*512 + ln*8;   // qo=0, kc0=2kh
    const _Float16* A1b = A0b + (size_t)K2*4*512;           // qo=1

    f32x16 acc0, acc1;
    #pragma unroll
    for (int i = 0; i < 16; ++i) { acc0[i] = 0.f; acc1[i] = 0.f; }

    int di = 0, dj = 0;
    #pragma unroll 7
    for (int tap = 0; tap < K2; ++tap) {
        const _Float16* a0 = A0b + (size_t)tap*2048;
        half8 A00 = *(const half8*)(a0);
        half8 A01 = *(const half8*)(a0 + 512);
        const _Float16* a1 = A1b + (size_t)tap*2048;
        half8 A10 = *(const half8*)(a1);
        half8 A11 = *(const half8*)(a1 + 512);

        int pos = (ppy + di)*PS + (ppx + dj);
        int sw  = pos & 7;
        const unsigned short* bbase = &xpT[pos*64];
        half8 B0 = *(const half8*)(bbase + ((jc0 ^ sw) << 3));
        half8 B1 = *(const half8*)(bbase + ((jc1 ^ sw) << 3));

        _Float16 rv = __builtin_bit_cast(_Float16, rwb[tap*64 + p]);
        half8 rv8 = { rv, rv, rv, rv, rv, rv, rv, rv };
        B0 *= rv8;
        B1 *= rv8;

        acc0 = __builtin_amdgcn_mfma_f32_32x32x16_f16(A00, B0, acc0, 0, 0, 0);
        acc0 = __builtin_amdgcn_mfma_f32_32x32x16_f16(A01, B1, acc0, 0, 0, 0);
        acc1 = __builtin_amdgcn_mfma_f32_32x32x16_f16(A10, B0, acc1, 0, 0, 0);
        acc1 = __builtin_amdgcn_mfma_f32_32x32x16_f16(A11, B1, acc1, 0, 0, 0);

        if (++dj == KS) { dj = 0; ++di; }
    }

    // cross-kh reduction (reuse xpT as f32 buffer: (qp,qoacc,reg) x 64 lanes = 16 KB)
    __syncthreads();
    float* red = (float*)xpT;
    if (kh == 1) {
        #pragma unroll
        for (int i = 0; i < 16; ++i) {
            red[((qp*2 + 0)*16 + i)*64 + ln] = acc0[i];
            red[((qp*2 + 1)*16 + i)*64 + ln] = acc1[i];
        }
    }
    __syncthreads();
    if (kh == 0) {
        int h = th0 + ppy, w = tw0 + ppx;
        int row_hi = 4*lhi;
        float* ob = out + (size_t)t*OO*HWSZ + h*WW + w;
        #pragma unroll
        for (int rg = 0; rg < 16; ++rg) {
            int o0 = (rg & 3) + 8*(rg >> 2) + row_hi;
            int o1 = 32 + o0;
            float v0 = acc0[rg] + red[((qp*2 + 0)*16 + rg)*64 + ln];
            float v1 = acc1[rg] + red[((qp*2 + 1)*16 + rg)*64 + ln];
            ob[(size_t)o0*HWSZ] = v0 + b_lin[o0];
            ob[(size_t)o1*HWSZ] = v1 + b_lin[o1];
        }
    }
}

extern "C" void kernel_launch(void* const* d_in, const int* in_sizes, int n_in,
                              void* d_out, int out_size, void* d_ws, size_t ws_size,
                              hipStream_t stream) {
    const float* x    = (const float*)d_in[0];
    const int*   spix = (const int*)d_in[1];
    const float* Wl   = (const float*)d_in[2];
    const float* bl   = (const float*)d_in[3];
    const float* wsc  = (const float*)d_in[4];
    const float* bsc  = (const float*)d_in[5];
    float* out = (float*)d_out;

    float* ws    = (float*)d_ws;
    float* sums  = ws;                           // 25088 f32
    float* cnts  = sums + TT*NSPIX*CC;           // 392
    float* pwd   = cnts + TT*NSPIX;              // 76832
    float* scale = pwd  + TT*NSPIX*NSPIX;        // 51200
    _Float16* Wb = (_Float16*)(scale + TT*HWSZ); // 200704 f16
    _Float16* xT = Wb + (size_t)2*K2*4*64*8;     // 3276800 f16 (6.55 MB)

    hipMemsetAsync(sums, 0, (size_t)(TT*NSPIX*CC + TT*NSPIX)*sizeof(float), stream);

    k_prep<<<1196, 256, 0, stream>>>(x, spix, Wl, wsc, bsc, sums, cnts, scale, Wb, xT);
    k_pwd <<<(TT*NSPIX*NSPIX + 255)/256, 256, 0, stream>>>(sums, cnts, pwd);

    dim3 blk(64, 4, 1);
    k_main<<<TT*400, blk, 0, stream>>>(xT, spix, Wb, bl, pwd, scale, out);
}